// Round 9
// baseline (751.683 us; speedup 1.0000x reference)
//
#include <hip/hip_runtime.h>
#include <hip/hip_bf16.h>
#include <math.h>

// Problem constants
#define BB 16
#define QQ 100
#define NH 8
#define HWN 4096
#define NORM_FACT 0.17677669529663687f   // 32^-0.5
#define QPAD 112        // q rows padded to 112 (7 tiles of 16)
#define NSLOT 2048      // partial slots per (b,q): 64 hwblocks * 4 waves * 8 heads

typedef short bf16x8_t __attribute__((ext_vector_type(8)));
typedef float f32x4_t  __attribute__((ext_vector_type(4)));

__device__ __forceinline__ unsigned short bf16bits(float f) {
    __hip_bfloat16 h = __float2bfloat16(f);           // RNE
    return __builtin_bit_cast(unsigned short, h);
}
__device__ __forceinline__ float bf16tof(unsigned short u) {
    union { unsigned int i; float f; } x; x.i = (unsigned int)u << 16; return x.f;
}

// ---------------- K0: WqT (fp32 transpose) + Wk -> bf16 -----------------------
__global__ void k_prep(const float* __restrict__ Wq, const float* __restrict__ Wk,
                       float* __restrict__ WqT, unsigned short* __restrict__ Wkbf) {
    int idx = blockIdx.x;
    int h = threadIdx.x;
    if (idx < 256) {
        WqT[idx * 256 + h] = Wq[h * 256 + idx];
    } else {
        int r = idx - 256;
        Wkbf[r * 256 + h] = bf16bits(Wk[r * 256 + h]);
    }
}

// ---------------- K1: q-proj -> bf16 hi/lo split, padded to 112 rows ----------
__global__ __launch_bounds__(256) void k_qproj(const float* __restrict__ q,
                                               const float* __restrict__ WqT,
                                               const float* __restrict__ bq,
                                               unsigned short* __restrict__ qphi,
                                               unsigned short* __restrict__ qplo) {
    int blk = blockIdx.x;             // 16 b x 28 tiles of 4 rows
    int b = blk / 28, q0 = (blk % 28) * 4;
    int h = threadIdx.x;
    size_t obase = ((size_t)b * QPAD + q0) * 256 + h;
    if (q0 >= QQ) {                   // padding rows -> zeros
#pragma unroll
        for (int i = 0; i < 4; ++i) { qphi[obase + i * 256] = 0; qplo[obase + i * 256] = 0; }
        return;
    }
    __shared__ float qsh[4][256];
    int ibase = (b * QQ + q0) * 256;
#pragma unroll
    for (int i = 0; i < 4; ++i) qsh[i][h] = q[ibase + i * 256 + h];
    __syncthreads();
    float bias = bq[h];
    float a0 = bias, a1 = bias, a2 = bias, a3 = bias;
    for (int c = 0; c < 256; ++c) {
        float wv = WqT[c * 256 + h];
        a0 = fmaf(qsh[0][c], wv, a0);
        a1 = fmaf(qsh[1][c], wv, a1);
        a2 = fmaf(qsh[2][c], wv, a2);
        a3 = fmaf(qsh[3][c], wv, a3);
    }
    float a[4] = {a0 * NORM_FACT, a1 * NORM_FACT, a2 * NORM_FACT, a3 * NORM_FACT};
#pragma unroll
    for (int i = 0; i < 4; ++i) {
        unsigned short hi = bf16bits(a[i]);
        qphi[obase + i * 256] = hi;
        qplo[obase + i * 256] = bf16bits(a[i] - bf16tof(hi));
    }
}

// ---------------- K2: fused transpose + kproj (DIAGNOSTIC: reps loop) ---------
__global__ __launch_bounds__(256) void k_kproj2(const float* __restrict__ k,
                                                const unsigned short* __restrict__ Wkbf,
                                                const float* __restrict__ bk,
                                                unsigned short* __restrict__ kpT,
                                                int reps) {
    int b = blockIdx.y;
    int hwblk = blockIdx.x * 32;
    int t = threadIdx.x;
    int w = t >> 6, lane = t & 63;
    int hwt = w & 1, oh = w >> 1;
    int n15 = lane & 15, kg = lane >> 4;

    __shared__ float lds_f[32][268];
#pragma unroll 1
    for (int rep = 0; rep < reps; ++rep) {
        int off0 = 0; asm volatile("" : "+v"(off0));   // opaque 0: defeat hoisting
        __syncthreads();   // protect LDS reuse across reps
        {
            const float* kb = k + (size_t)b * 256 * HWN + hwblk + off0;
            int c_l = t >> 3, l8 = t & 7;
#pragma unroll
            for (int it = 0; it < 8; ++it) {
                int c = it * 32 + c_l;
                float4 v = *(const float4*)(kb + (size_t)c * HWN + l8 * 4);
                lds_f[l8 * 4 + 0][c] = v.x;
                lds_f[l8 * 4 + 1][c] = v.y;
                lds_f[l8 * 4 + 2][c] = v.z;
                lds_f[l8 * 4 + 3][c] = v.w;
            }
        }
        __syncthreads();

        f32x4_t acc[8];
#pragma unroll
        for (int m = 0; m < 8; ++m) acc[m] = f32x4_t{0.f, 0.f, 0.f, 0.f};

        const unsigned short* wbase = Wkbf + ((size_t)(oh * 128 + n15)) * 256 + kg * 8 + off0;
        int hw_l = hwt * 16 + n15;

#pragma unroll
        for (int ks = 0; ks < 8; ++ks) {
            f32x4_t f0 = *(const f32x4_t*)&lds_f[hw_l][ks * 32 + kg * 8];
            f32x4_t f1 = *(const f32x4_t*)&lds_f[hw_l][ks * 32 + kg * 8 + 4];
            bf16x8_t bfrag;
#pragma unroll
            for (int j = 0; j < 4; ++j) {
                bfrag[j]     = (short)bf16bits(f0[j]);
                bfrag[4 + j] = (short)bf16bits(f1[j]);
            }
#pragma unroll
            for (int m = 0; m < 8; ++m) {
                bf16x8_t afrag = *reinterpret_cast<const bf16x8_t*>(wbase + (size_t)m * 16 * 256 + ks * 32);
                acc[m] = __builtin_amdgcn_mfma_f32_16x16x32_bf16(afrag, bfrag, acc[m], 0, 0, 0);
            }
        }
        __syncthreads();

        unsigned short* tile2 = (unsigned short*)lds_f;
#pragma unroll
        for (int m = 0; m < 8; ++m) {
            ushort4 pk;
            unsigned short* pkp = (unsigned short*)&pk;
#pragma unroll
            for (int r = 0; r < 4; ++r) {
                int o = oh * 128 + m * 16 + kg * 4 + r;
                pkp[r] = bf16bits(acc[m][r] + bk[o]);
            }
            *(ushort4*)&tile2[(size_t)hw_l * 264 + oh * 128 + m * 16 + kg * 4] = pk;
        }
        __syncthreads();
        int row = t >> 3, sub = t & 7;
        unsigned short* dst = kpT + ((size_t)b * HWN + hwblk + row) * 256 + sub * 32 + off0;
        const unsigned short* srcl = &tile2[(size_t)row * 264 + sub * 32];
#pragma unroll
        for (int j = 0; j < 4; ++j)
            *(uint4*)(dst + j * 8) = *(const uint4*)(srcl + j * 8);
    }
}

// ---------------- K3: sum-pass, head-split (DIAGNOSTIC: reps loop) ------------
__global__ __launch_bounds__(256) void k_sums(const unsigned short* __restrict__ qphi,
                                              const unsigned short* __restrict__ qplo,
                                              const unsigned short* __restrict__ kpT,
                                              const int* __restrict__ mask,
                                              float* __restrict__ partial,
                                              int reps) {
    int hwb = blockIdx.x, n = blockIdx.y, b = blockIdx.z;
    int t = threadIdx.x, w = t >> 6, lane = t & 63;
    int n15 = lane & 15, kg = lane >> 4;
    int hw = hwb * 64 + w * 16 + n15;
    float mm = mask[b * HWN + hw] ? 0.0f : 1.0f;
    int slot = (hwb * 4 + w) * 8 + n;
#pragma unroll 1
    for (int rep = 0; rep < reps; ++rep) {
        int off0 = 0; asm volatile("" : "+v"(off0));
        bf16x8_t bfr = *reinterpret_cast<const bf16x8_t*>(
            kpT + ((size_t)(b * HWN + hw)) * 256 + n * 32 + kg * 8 + off0);
        const unsigned short* ahi_b = qphi + ((size_t)(b * QPAD + n15)) * 256 + n * 32 + kg * 8 + off0;
        const unsigned short* alo_b = qplo + ((size_t)(b * QPAD + n15)) * 256 + n * 32 + kg * 8 + off0;
        float* pbase = partial + (size_t)b * QPAD * NSLOT + slot;
#pragma unroll
        for (int mt = 0; mt < 7; ++mt) {
            bf16x8_t ahi = *reinterpret_cast<const bf16x8_t*>(ahi_b + (size_t)(mt * 16) * 256);
            bf16x8_t alo = *reinterpret_cast<const bf16x8_t*>(alo_b + (size_t)(mt * 16) * 256);
            f32x4_t a2 = {0.f, 0.f, 0.f, 0.f};
            a2 = __builtin_amdgcn_mfma_f32_16x16x32_bf16(ahi, bfr, a2, 0, 0, 0);
            a2 = __builtin_amdgcn_mfma_f32_16x16x32_bf16(alo, bfr, a2, 0, 0, 0);
#pragma unroll
            for (int r = 0; r < 4; ++r) {
                float v = __expf(a2[r]) * mm;
                v += __shfl_xor(v, 1, 64);
                v += __shfl_xor(v, 2, 64);
                v += __shfl_xor(v, 4, 64);
                v += __shfl_xor(v, 8, 64);
                if (n15 == 0)
                    pbase[(size_t)(mt * 16 + kg * 4 + r) * NSLOT] = v;
            }
        }
    }
}

// ---------------- K4: inv_sum[b,q] — one block per (b,q), 2048-slot reduce ----
__global__ __launch_bounds__(256) void k_invsum(const float* __restrict__ partial,
                                                float* __restrict__ inv) {
    int blk = blockIdx.x;            // 0..1599
    int b = blk / QQ, qq = blk % QQ;
    const float* p = partial + ((size_t)b * QPAD + qq) * NSLOT;
    int t = threadIdx.x;
    float v = 0.0f;
#pragma unroll
    for (int j = 0; j < NSLOT / 256; ++j) v += p[t + j * 256];
#pragma unroll
    for (int off = 32; off; off >>= 1) v += __shfl_xor(v, off, 64);
    __shared__ float red[4];
    if ((t & 63) == 0) red[t >> 6] = v;
    __syncthreads();
    if (t == 0) inv[blk] = 1.0f / (red[0] + red[1] + red[2] + red[3]);
}

// ---------------- K5: write-pass, head-split (DIAGNOSTIC: reps loop) ----------
__global__ __launch_bounds__(256) void k_write(const unsigned short* __restrict__ qphi,
                                               const unsigned short* __restrict__ qplo,
                                               const unsigned short* __restrict__ kpT,
                                               const int* __restrict__ mask,
                                               const float* __restrict__ inv,
                                               float* __restrict__ out,
                                               int reps) {
    int hws = blockIdx.x, n = blockIdx.y, b = blockIdx.z;
    int t = threadIdx.x, w = t >> 6, lane = t & 63;
    int n15 = lane & 15, kg = lane >> 4;
    int hw0 = hws * 256 + w * 64;
    float mm[4];
#pragma unroll
    for (int ht = 0; ht < 4; ++ht)
        mm[ht] = mask[b * HWN + hw0 + ht * 16 + n15] ? 0.0f : 1.0f;
#pragma unroll 1
    for (int rep = 0; rep < reps; ++rep) {
        int off0 = 0; asm volatile("" : "+v"(off0));
        bf16x8_t bf[4];
#pragma unroll
        for (int ht = 0; ht < 4; ++ht)
            bf[ht] = *reinterpret_cast<const bf16x8_t*>(
                kpT + ((size_t)(b * HWN + hw0 + ht * 16 + n15)) * 256 + n * 32 + kg * 8 + off0);
        const unsigned short* ahi_b = qphi + ((size_t)(b * QPAD + n15)) * 256 + n * 32 + kg * 8 + off0;
        const unsigned short* alo_b = qplo + ((size_t)(b * QPAD + n15)) * 256 + n * 32 + kg * 8 + off0;
#pragma unroll 2
        for (int qt = 0; qt < 7; ++qt) {
            bf16x8_t ahi = *reinterpret_cast<const bf16x8_t*>(ahi_b + (size_t)(qt * 16) * 256);
            bf16x8_t alo = *reinterpret_cast<const bf16x8_t*>(alo_b + (size_t)(qt * 16) * 256);
            float invq[4];
#pragma unroll
            for (int r = 0; r < 4; ++r) {
                int qrow = qt * 16 + kg * 4 + r;
                invq[r] = (qrow < QQ) ? inv[b * QQ + qrow] : 0.0f;
            }
#pragma unroll
            for (int ht = 0; ht < 4; ++ht) {
                f32x4_t acc = {0.f, 0.f, 0.f, 0.f};
                acc = __builtin_amdgcn_mfma_f32_16x16x32_bf16(ahi, bf[ht], acc, 0, 0, 0);
                acc = __builtin_amdgcn_mfma_f32_16x16x32_bf16(alo, bf[ht], acc, 0, 0, 0);
#pragma unroll
                for (int r = 0; r < 4; ++r) {
                    int qrow = qt * 16 + kg * 4 + r;
                    float v = __expf(acc[r]) * mm[ht] * invq[r];
                    if (qrow < QQ)
                        __builtin_nontemporal_store(v,
                            out + (((size_t)(b * QQ + qrow)) * NH + n) * HWN + hw0 + ht * 16 + n15);
                }
            }
        }
    }
}

extern "C" void kernel_launch(void* const* d_in, const int* in_sizes, int n_in,
                              void* d_out, int out_size, void* d_ws, size_t ws_size,
                              hipStream_t stream) {
    const float* q    = (const float*)d_in[0];
    const float* k    = (const float*)d_in[1];
    const float* Wq   = (const float*)d_in[2];
    const float* bq   = (const float*)d_in[3];
    const float* Wk   = (const float*)d_in[4];
    const float* bk   = (const float*)d_in[5];
    const int*   mask = (const int*)d_in[6];
    float* out = (float*)d_out;

    char* base = (char*)d_ws;
    unsigned short* kpT  = (unsigned short*)(base);              // 33,554,432 B
    unsigned short* qphi = (unsigned short*)(base + 33554432);   //    917,504 B
    unsigned short* qplo = (unsigned short*)(base + 34471936);   //    917,504 B
    float*  WqT     = (float*)(base + 35389440);                 //    262,144 B
    unsigned short* Wkbf = (unsigned short*)(base + 35651584);   //    131,072 B
    float*  partial = (float*)(base + 35782656);                 // 14,680,064 B
    float*  inv     = (float*)(base + 50462720);                 //      6,400 B
    if (ws_size < (size_t)50469120) return;

    k_prep  <<<dim3(512), dim3(256), 0, stream>>>(Wq, Wk, WqT, Wkbf);
    k_qproj <<<dim3(448), dim3(256), 0, stream>>>(q, WqT, bq, qphi, qplo);
    k_kproj2<<<dim3(128, 16), dim3(256), 0, stream>>>(k, Wkbf, bk, kpT, 4);
    k_sums  <<<dim3(64, 8, 16), dim3(256), 0, stream>>>(qphi, qplo, kpT, mask, partial, 4);
    k_invsum<<<dim3(1600), dim3(256), 0, stream>>>(partial, inv);
    k_write <<<dim3(16, 8, 16), dim3(256), 0, stream>>>(qphi, qplo, kpT, mask, inv, out, 3);
}

// Round 10
// 203.483 us; speedup vs baseline: 3.6941x; 3.6941x over previous
//
#include <hip/hip_runtime.h>
#include <hip/hip_bf16.h>
#include <math.h>

// Problem constants
#define BB 16
#define QQ 100
#define NH 8
#define HWN 4096
#define NORM_FACT 0.17677669529663687f   // 32^-0.5
#define QPAD 112        // q rows padded to 112 (7 tiles of 16)
#define NSLOT 2048      // partial slots per (b,q): 64 hwblocks * 4 waves * 8 heads

typedef short bf16x8_t __attribute__((ext_vector_type(8)));
typedef float f32x4_t  __attribute__((ext_vector_type(4)));

__device__ __forceinline__ unsigned short bf16bits(float f) {
    __hip_bfloat16 h = __float2bfloat16(f);           // RNE
    return __builtin_bit_cast(unsigned short, h);
}
__device__ __forceinline__ float bf16tof(unsigned short u) {
    union { unsigned int i; float f; } x; x.i = (unsigned int)u << 16; return x.f;
}

// ---------------- K0: WqT (fp32 transpose) + Wk -> bf16 -----------------------
__global__ void k_prep(const float* __restrict__ Wq, const float* __restrict__ Wk,
                       float* __restrict__ WqT, unsigned short* __restrict__ Wkbf) {
    int idx = blockIdx.x;
    int h = threadIdx.x;
    if (idx < 256) {
        WqT[idx * 256 + h] = Wq[h * 256 + idx];
    } else {
        int r = idx - 256;
        Wkbf[r * 256 + h] = bf16bits(Wk[r * 256 + h]);
    }
}

// ---------------- K1: q-proj -> bf16 hi/lo split, padded to 112 rows ----------
__global__ __launch_bounds__(256) void k_qproj(const float* __restrict__ q,
                                               const float* __restrict__ WqT,
                                               const float* __restrict__ bq,
                                               unsigned short* __restrict__ qphi,
                                               unsigned short* __restrict__ qplo) {
    int blk = blockIdx.x;             // 16 b x 28 tiles of 4 rows
    int b = blk / 28, q0 = (blk % 28) * 4;
    int h = threadIdx.x;
    size_t obase = ((size_t)b * QPAD + q0) * 256 + h;
    if (q0 >= QQ) {                   // padding rows -> zeros
#pragma unroll
        for (int i = 0; i < 4; ++i) { qphi[obase + i * 256] = 0; qplo[obase + i * 256] = 0; }
        return;
    }
    __shared__ float qsh[4][256];
    int ibase = (b * QQ + q0) * 256;
#pragma unroll
    for (int i = 0; i < 4; ++i) qsh[i][h] = q[ibase + i * 256 + h];
    __syncthreads();
    float bias = bq[h];
    float a0 = bias, a1 = bias, a2 = bias, a3 = bias;
    for (int c = 0; c < 256; ++c) {
        float wv = WqT[c * 256 + h];
        a0 = fmaf(qsh[0][c], wv, a0);
        a1 = fmaf(qsh[1][c], wv, a1);
        a2 = fmaf(qsh[2][c], wv, a2);
        a3 = fmaf(qsh[3][c], wv, a3);
    }
    float a[4] = {a0 * NORM_FACT, a1 * NORM_FACT, a2 * NORM_FACT, a3 * NORM_FACT};
#pragma unroll
    for (int i = 0; i < 4; ++i) {
        unsigned short hi = bf16bits(a[i]);
        qphi[obase + i * 256] = hi;
        qplo[obase + i * 256] = bf16bits(a[i] - bf16tof(hi));
    }
}

// ---------------- K2: fused transpose+kproj, 256B k-reads, slim LDS -----------
// grid (64 hwblk-of-64, 16 b), 512 threads (8 waves). Wave = 16 hw x 128 o.
// k staged fp32 in c-chunks of 128 (LDS [64][140], pad->uniform bank groups),
// reused as the bf16 output-transpose tile. kpT written 512B/row, 32KB/block.
__global__ __launch_bounds__(512) void k_kproj3(const float* __restrict__ k,
                                                const unsigned short* __restrict__ Wkbf,
                                                const float* __restrict__ bk,
                                                unsigned short* __restrict__ kpT) {
    int b = blockIdx.y;
    int hwblk = blockIdx.x * 64;
    int t = threadIdx.x;
    int w = t >> 6, lane = t & 63;
    int hwt = w & 3, oh = w >> 2;          // wave -> (16-hw tile, 128-o half)
    int n15 = lane & 15, kg = lane >> 4;
    int hw_l = hwt * 16 + n15;

    __shared__ float lds_f[64][140];       // 35,840 B

    f32x4_t acc[8];
#pragma unroll
    for (int m = 0; m < 8; ++m) acc[m] = f32x4_t{0.f, 0.f, 0.f, 0.f};

    const float* kb = k + (size_t)b * 256 * HWN + hwblk;
    const unsigned short* wbase = Wkbf + ((size_t)(oh * 128 + n15)) * 256 + kg * 8;
    int c_l = t >> 4, l16 = t & 15;        // staging roles: 32 c-rows x 16 lanes(256B)

#pragma unroll
    for (int chunk = 0; chunk < 2; ++chunk) {
        // stage [128 c][64 hw] fp32: per instr 32 rows x 256B contiguous
#pragma unroll
        for (int p = 0; p < 4; ++p) {
            int cc = p * 32 + c_l;                         // 0..127 within chunk
            float4 v = *(const float4*)(kb + (size_t)(chunk * 128 + cc) * HWN + l16 * 4);
            lds_f[l16 * 4 + 0][cc] = v.x;
            lds_f[l16 * 4 + 1][cc] = v.y;
            lds_f[l16 * 4 + 2][cc] = v.z;
            lds_f[l16 * 4 + 3][cc] = v.w;
        }
        __syncthreads();
#pragma unroll
        for (int ksl = 0; ksl < 4; ++ksl) {
            f32x4_t f0 = *(const f32x4_t*)&lds_f[hw_l][ksl * 32 + kg * 8];
            f32x4_t f1 = *(const f32x4_t*)&lds_f[hw_l][ksl * 32 + kg * 8 + 4];
            bf16x8_t bfrag;
#pragma unroll
            for (int j = 0; j < 4; ++j) {
                bfrag[j]     = (short)bf16bits(f0[j]);
                bfrag[4 + j] = (short)bf16bits(f1[j]);
            }
            int ks = chunk * 4 + ksl;
#pragma unroll
            for (int m = 0; m < 8; ++m) {
                bf16x8_t afrag = *reinterpret_cast<const bf16x8_t*>(wbase + (size_t)m * 16 * 256 + ks * 32);
                acc[m] = __builtin_amdgcn_mfma_f32_16x16x32_bf16(afrag, bfrag, acc[m], 0, 0, 0);
            }
        }
        __syncthreads();   // done reading this chunk before restage/reuse
    }

    // epilogue: bias + bf16 -> tile2 [64 hw][264 o] (reuses lds_f: 33,792B)
    unsigned short* tile2 = (unsigned short*)lds_f;
#pragma unroll
    for (int m = 0; m < 8; ++m) {
        ushort4 pk;
        unsigned short* pkp = (unsigned short*)&pk;
#pragma unroll
        for (int r = 0; r < 4; ++r) {
            int o = oh * 128 + m * 16 + kg * 4 + r;
            pkp[r] = bf16bits(acc[m][r] + bk[o]);
        }
        *(ushort4*)&tile2[(size_t)hw_l * 264 + oh * 128 + m * 16 + kg * 4] = pk;
    }
    __syncthreads();
    // write out: each half-wave emits one full 512B kpT row
    int l5 = t & 31;
#pragma unroll
    for (int it = 0; it < 4; ++it) {
        int row = it * 16 + (t >> 5);
        uint4 v = *(const uint4*)&tile2[(size_t)row * 264 + l5 * 8];
        *(uint4*)(kpT + ((size_t)b * HWN + hwblk + row) * 256 + l5 * 8) = v;
    }
}

// ---------------- K3: sum-pass, head-split — 1 B-frag + 14 MFMA per wave ------
// grid (64 hwblocks of 64, 8 heads, 16 b); 4 waves; wave = one 16-hw tile
__global__ __launch_bounds__(256) void k_sums(const unsigned short* __restrict__ qphi,
                                              const unsigned short* __restrict__ qplo,
                                              const unsigned short* __restrict__ kpT,
                                              const int* __restrict__ mask,
                                              float* __restrict__ partial) {
    int hwb = blockIdx.x, n = blockIdx.y, b = blockIdx.z;
    int t = threadIdx.x, w = t >> 6, lane = t & 63;
    int n15 = lane & 15, kg = lane >> 4;
    int hw = hwb * 64 + w * 16 + n15;
    float mm = mask[b * HWN + hw] ? 0.0f : 1.0f;
    bf16x8_t bfr = *reinterpret_cast<const bf16x8_t*>(
        kpT + ((size_t)(b * HWN + hw)) * 256 + n * 32 + kg * 8);
    const unsigned short* ahi_b = qphi + ((size_t)(b * QPAD + n15)) * 256 + n * 32 + kg * 8;
    const unsigned short* alo_b = qplo + ((size_t)(b * QPAD + n15)) * 256 + n * 32 + kg * 8;
    int slot = (hwb * 4 + w) * 8 + n;
    float* pbase = partial + (size_t)b * QPAD * NSLOT + slot;
#pragma unroll
    for (int mt = 0; mt < 7; ++mt) {
        bf16x8_t ahi = *reinterpret_cast<const bf16x8_t*>(ahi_b + (size_t)(mt * 16) * 256);
        bf16x8_t alo = *reinterpret_cast<const bf16x8_t*>(alo_b + (size_t)(mt * 16) * 256);
        f32x4_t a2 = {0.f, 0.f, 0.f, 0.f};
        a2 = __builtin_amdgcn_mfma_f32_16x16x32_bf16(ahi, bfr, a2, 0, 0, 0);
        a2 = __builtin_amdgcn_mfma_f32_16x16x32_bf16(alo, bfr, a2, 0, 0, 0);
#pragma unroll
        for (int r = 0; r < 4; ++r) {
            float v = __expf(a2[r]) * mm;
            v += __shfl_xor(v, 1, 64);
            v += __shfl_xor(v, 2, 64);
            v += __shfl_xor(v, 4, 64);
            v += __shfl_xor(v, 8, 64);
            if (n15 == 0)
                pbase[(size_t)(mt * 16 + kg * 4 + r) * NSLOT] = v;
        }
    }
}

// ---------------- K4: inv_sum[b,q] — one block per (b,q), 2048-slot reduce ----
__global__ __launch_bounds__(256) void k_invsum(const float* __restrict__ partial,
                                                float* __restrict__ inv) {
    int blk = blockIdx.x;            // 0..1599
    int b = blk / QQ, qq = blk % QQ;
    const float* p = partial + ((size_t)b * QPAD + qq) * NSLOT;
    int t = threadIdx.x;
    float v = 0.0f;
#pragma unroll
    for (int j = 0; j < NSLOT / 256; ++j) v += p[t + j * 256];
#pragma unroll
    for (int off = 32; off; off >>= 1) v += __shfl_xor(v, off, 64);
    __shared__ float red[4];
    if ((t & 63) == 0) red[t >> 6] = v;
    __syncthreads();
    if (t == 0) inv[blk] = 1.0f / (red[0] + red[1] + red[2] + red[3]);
}

// ---------------- K5: write-pass — per-wave LDS transpose, 256B f32x4 stores --
// grid (16 hw strips of 256, 8 heads, 16 b); wave owns 64 hw (4 ht tiles)
__global__ __launch_bounds__(256) void k_write(const unsigned short* __restrict__ qphi,
                                               const unsigned short* __restrict__ qplo,
                                               const unsigned short* __restrict__ kpT,
                                               const int* __restrict__ mask,
                                               const float* __restrict__ inv,
                                               float* __restrict__ out) {
    int hws = blockIdx.x, n = blockIdx.y, b = blockIdx.z;
    int t = threadIdx.x, w = t >> 6, lane = t & 63;
    int n15 = lane & 15, kg = lane >> 4;
    int hw0 = hws * 256 + w * 64;
    float mm[4];
#pragma unroll
    for (int ht = 0; ht < 4; ++ht)
        mm[ht] = mask[b * HWN + hw0 + ht * 16 + n15] ? 0.0f : 1.0f;
    bf16x8_t bf[4];
#pragma unroll
    for (int ht = 0; ht < 4; ++ht)
        bf[ht] = *reinterpret_cast<const bf16x8_t*>(
            kpT + ((size_t)(b * HWN + hw0 + ht * 16 + n15)) * 256 + n * 32 + kg * 8);
    const unsigned short* ahi_b = qphi + ((size_t)(b * QPAD + n15)) * 256 + n * 32 + kg * 8;
    const unsigned short* alo_b = qplo + ((size_t)(b * QPAD + n15)) * 256 + n * 32 + kg * 8;
    __shared__ float lt[4][16][68];   // per-wave 16q x 64hw staging
#pragma unroll 1
    for (int qt = 0; qt < 7; ++qt) {
        bf16x8_t ahi = *reinterpret_cast<const bf16x8_t*>(ahi_b + (size_t)(qt * 16) * 256);
        bf16x8_t alo = *reinterpret_cast<const bf16x8_t*>(alo_b + (size_t)(qt * 16) * 256);
        float invq[4];
#pragma unroll
        for (int r = 0; r < 4; ++r) {
            int qrow = qt * 16 + kg * 4 + r;
            invq[r] = (qrow < QQ) ? inv[b * QQ + qrow] : 0.0f;
        }
#pragma unroll
        for (int ht = 0; ht < 4; ++ht) {
            f32x4_t acc = {0.f, 0.f, 0.f, 0.f};
            acc = __builtin_amdgcn_mfma_f32_16x16x32_bf16(ahi, bf[ht], acc, 0, 0, 0);
            acc = __builtin_amdgcn_mfma_f32_16x16x32_bf16(alo, bf[ht], acc, 0, 0, 0);
#pragma unroll
            for (int r = 0; r < 4; ++r)
                lt[w][kg * 4 + r][ht * 16 + n15] = __expf(acc[r]) * mm[ht] * invq[r];
        }
        // per-wave LDS RAW: compiler inserts lgkmcnt wait; no barrier needed
#pragma unroll
        for (int j = 0; j < 4; ++j) {
            int rr = j * 4 + kg;
            int qrow = qt * 16 + rr;
            f32x4_t v4 = *(const f32x4_t*)&lt[w][rr][n15 * 4];
            if (qrow < QQ)
                *(f32x4_t*)(out + (((size_t)(b * QQ + qrow)) * NH + n) * HWN + hw0 + n15 * 4) = v4;
        }
    }
}

extern "C" void kernel_launch(void* const* d_in, const int* in_sizes, int n_in,
                              void* d_out, int out_size, void* d_ws, size_t ws_size,
                              hipStream_t stream) {
    const float* q    = (const float*)d_in[0];
    const float* k    = (const float*)d_in[1];
    const float* Wq   = (const float*)d_in[2];
    const float* bq   = (const float*)d_in[3];
    const float* Wk   = (const float*)d_in[4];
    const float* bk   = (const float*)d_in[5];
    const int*   mask = (const int*)d_in[6];
    float* out = (float*)d_out;

    char* base = (char*)d_ws;
    unsigned short* kpT  = (unsigned short*)(base);              // 33,554,432 B
    unsigned short* qphi = (unsigned short*)(base + 33554432);   //    917,504 B
    unsigned short* qplo = (unsigned short*)(base + 34471936);   //    917,504 B
    float*  WqT     = (float*)(base + 35389440);                 //    262,144 B
    unsigned short* Wkbf = (unsigned short*)(base + 35651584);   //    131,072 B
    float*  partial = (float*)(base + 35782656);                 // 14,680,064 B
    float*  inv     = (float*)(base + 50462720);                 //      6,400 B
    if (ws_size < (size_t)50469120) return;

    k_prep  <<<dim3(512), dim3(256), 0, stream>>>(Wq, Wk, WqT, Wkbf);
    k_qproj <<<dim3(448), dim3(256), 0, stream>>>(q, WqT, bq, qphi, qplo);
    k_kproj3<<<dim3(64, 16), dim3(512), 0, stream>>>(k, Wkbf, bk, kpT);
    k_sums  <<<dim3(64, 8, 16), dim3(256), 0, stream>>>(qphi, qplo, kpT, mask, partial);
    k_invsum<<<dim3(1600), dim3(256), 0, stream>>>(partial, inv);
    k_write <<<dim3(16, 8, 16), dim3(256), 0, stream>>>(qphi, qplo, kpT, mask, inv, out);
}